// Round 14
// baseline (610.794 us; speedup 1.0000x reference)
//
#include <hip/hip_runtime.h>
#include <hip/hip_bf16.h>

// Keep every fp op matching numpy/jax f32 op-by-op rounding (no fma fusion):
#pragma clang fp contract(off)

#define NUM_CLASSES 100
#define B_DIM 8
#define N_DIM 32768
#define TOPK_K 1024
#define ROW_F 105
#define CONF_THRE_F 0.001f
#define NMS_THRE_F 0.65f
#define OFFSET_F 241.0f   // MAX_DIM + 1
#define T0_F 0.95f        // prefilter threshold (fast path iff 1024<=C<=2048)
#define CAND_CAP 2048
#define ROWS_PER_BLK 128  // per 1024-thread block
#define BLK_PER_BAT 256   // decode blocks per batch
#define SLOT_CAP 32       // per-block candidate slots (lambda~5.1, P(>32)~1e-16)

typedef unsigned long long u64;
typedef unsigned int u32;
typedef unsigned short u16;

__device__ __forceinline__ u64 shfl64(u64 v, int src) {
    int lo = __shfl((int)(v & 0xFFFFFFFFull), src);
    int hi = __shfl((int)(v >> 32), src);
    return ((u64)(u32)hi << 32) | (u32)lo;
}
__device__ __forceinline__ u64 shfl_xor64(u64 v, int mask) {
    int lo = __shfl_xor((int)(v & 0xFFFFFFFFull), mask);
    int hi = __shfl_xor((int)(v >> 32), mask);
    return ((u64)(u32)hi << 32) | (u32)lo;
}

// key layout (54 bits): [ou(32) << 22] | [(32767-n)(15) << 7] | class(7)
__device__ __forceinline__ u32 key_bin1(u64 k) {   // ou bits 30..18, 0 if invalid
    return ((k >> 53) & 1ull) ? (u32)((k >> 40) & 0x1FFFull) : 0u;
}
__device__ __forceinline__ u32 key_bin2(u64 k) {   // ou bits 17..5
    return (u32)((k >> 27) & 0x1FFFull);
}

// wave-0 suffix scan over 8192-bin LDS hist (rotated reads). FALLBACK only.
__device__ __forceinline__ void scan_hist(const u32* h, u32 target,
                                          u32* binT_out, u32* c1_out) {
    const int lane = threadIdx.x & 63;
    const u32* hl = h + lane * 128;
    u32 partial = 0;
    for (int k = 0; k < 128; ++k) partial += hl[(k + lane) & 127];
    u32 v = partial;
#pragma unroll
    for (int off = 1; off < 64; off <<= 1) {
        u32 o = __shfl_down(v, off);
        if (lane + off < 64) v += o;
    }
    u32 above = v - partial;
    if (above < target && above + partial >= target) {
        u32 cum = above;
        int bin = lane * 128 + 127;
        for (;; --bin) {
            cum += h[bin];
            if (cum >= target) break;
        }
        *binT_out = (u32)bin;
        if (c1_out) *c1_out = cum - h[bin];
    }
}

// ---------------------------------------------------------------------------
// FUSED kernel: decode 128 rows/block; the block whose done-counter increment
// crosses a mod-256 boundary (works for ANY counter start value) runs
// select+NMS for its batch. All cross-call data hazards are closed by:
// (a) deterministic slot assignment (ballot compaction, not atomic order),
// (b) validity-gated counts (any count > SLOT_CAP forces the self-contained
//     fallback; all loops bounded by SLOT_CAP).
// ---------------------------------------------------------------------------
__global__ __launch_bounds__(1024, 8) void fused_kernel(
        const float* __restrict__ pred,
        u64* __restrict__ keys_g,            // fallback scratch only
        u64* __restrict__ candk_g,
        float4* __restrict__ candb_g,
        u32* __restrict__ cntb_g,
        u32* __restrict__ done_g,
        float* __restrict__ out) {
    // ---- shared memory, phase-overlaid ----
    alignas(16) __shared__ char SHM[54528];
    __shared__ u32 bcount, isLast_s, bad_s;
    __shared__ u64 keepm_s[16];
    __shared__ u64 wmin_s[16], wmax_s[16];
    __shared__ u64 kmin_s;
    __shared__ u32 shift_s;
    __shared__ u32 wsum[16], woff[16], total_s;
    __shared__ u32 bcnt[256], bfill[256], bstart[257];
    __shared__ u32 cls_cnt[100], cls_start[100], cls_fill[100];
    __shared__ u32 binT_s, binT2_s, C1_s, cntS_s;

    const int tid  = threadIdx.x;
    const int wid  = tid >> 6;
    const int lane = tid & 63;
    const int blk  = blockIdx.x;             // 2048
    const int bat  = blk >> 8;
    const int bi   = blk & (BLK_PER_BAT - 1);
    const int rb   = blk << 7;               // 128 rows per block

    // ======================= decode phase =======================
    float*  buf  = (float*)SHM;              // [0, 53760)
    u64*    lkey = (u64*)(SHM + 53760);      // [53760, 54016)
    float4* lbox = (float4*)(SHM + 54016);   // [54016, 54528)

    {   // stage 128 rows = 3360 float4, coalesced
        const float4* src = reinterpret_cast<const float4*>(pred + (size_t)rb * ROW_F);
        float4* dst = reinterpret_cast<float4*>(buf);
        float4 v0 = src[tid];
        float4 v1 = src[tid + 1024];
        float4 v2 = src[tid + 2048];
        float4 v3;
        if (tid < 288) v3 = src[tid + 3072];
        dst[tid]        = v0;
        dst[tid + 1024] = v1;
        dst[tid + 2048] = v2;
        if (tid < 288) dst[tid + 3072] = v3;
    }
    __syncthreads();

    {   // scan: 8 threads/row, 3-step shfl_xor lexicographic max
        const int row = tid >> 3;            // 0..127
        const int sub = tid & 7;
        const float* R = buf + row * ROW_F;
        const int p0 = (sub < 4) ? (5 + 13 * sub) : (57 + 12 * (sub - 4));
        u64 kk;
        {
            u32 bb = 0u, cz = 0u;
#pragma unroll
            for (int k = 0; k < 13; ++k) {
                // class scores >= 0: bit order == float order; strict '>' with
                // ascending position keeps the FIRST max (== jnp.argmax).
                if (k < 12 || sub < 4) {
                    const int p = p0 + k;
                    u32 bf = __float_as_uint(R[p]) | 0x80000000u;
                    u32 cf = (u32)(104 - p);
                    if (bf > bb) { bb = bf; cz = cf; }
                }
            }
            kk = ((u64)bb << 7) | (u64)cz;
            u64 o = shfl_xor64(kk, 1); if (o > kk) kk = o;
            o     = shfl_xor64(kk, 2); if (o > kk) kk = o;
            o     = shfl_xor64(kk, 4); if (o > kk) kk = o;
        }
        const u32 bb = (u32)(kk >> 7);
        const int cls = 99 - (int)(kk & 0x7Full);
        const float cmax = __uint_as_float(bb & 0x7FFFFFFFu);
        const float obj = R[4];
        const float score = obj * cmax;      // reference op order
        const bool valid = (score * cmax) >= CONF_THRE_F;
        const float mval = valid ? score : -1.0f;

        // deterministic slot assignment: ballot compaction (data-pure order)
        const bool want = (sub == 0) && (mval >= T0_F);
        const u64 wm = __ballot(want);
        const u32 posw = (u32)__popcll(wm & ((1ull << lane) - 1ull));
        if (lane == 0) wsum[wid] = (u32)__popcll(wm);
        __syncthreads();
        if (tid == 0) {
            u32 s = 0;
            for (int i = 0; i < 16; ++i) { woff[i] = s; s += wsum[i]; }
            bcount = s;
        }
        __syncthreads();
        if (want) {
            const u32 u  = __float_as_uint(mval);
            const u32 ou = (u & 0x80000000u) ? ~u : (u | 0x80000000u);
            const int r = rb + row;
            const u64 key = ((u64)ou << 22) |
                            ((u64)(u32)((r & (N_DIM - 1)) ^ (N_DIM - 1)) << 7) |
                            (u64)cls;
            u32 p = woff[wid] + posw;
            if (p < SLOT_CAP) {
                lkey[p] = key;
                lbox[p] = make_float4(R[0], R[1], R[2], R[3]);
            }
        }
    }
    __syncthreads();

    {   // publish per-block slots (deterministic contents)
        const u32 c = bcount;
        const u32 gslot = ((u32)bat * BLK_PER_BAT + (u32)bi) * SLOT_CAP;
        if (tid < c && tid < SLOT_CAP) {
            candk_g[gslot + tid] = lkey[tid];
            candb_g[gslot + tid] = lbox[tid];
        }
        if (tid == 0) cntb_g[bat * BLK_PER_BAT + bi] = (c <= SLOT_CAP) ? c : 0xFFFFu;
    }
    __threadfence();                          // release our writes (agent scope)
    __syncthreads();
    if (tid == 0) {
        u32 old = __hip_atomic_fetch_add(&done_g[bat << 5], 1u,
                                         __ATOMIC_ACQ_REL, __HIP_MEMORY_SCOPE_AGENT);
        // exactly one block per batch per call crosses a mod-256 boundary,
        // regardless of the counter's (poisoned/persistent) start value
        isLast_s = (((old + 1u) & (u32)(BLK_PER_BAT - 1)) == 0u) ? 1u : 0u;
    }
    __syncthreads();
    if (!isLast_s) return;
    __threadfence();                          // acquire side
    __syncthreads();

    // ======================= select + NMS phase (one block per batch) ======
    u64* candS    = (u64*)SHM;                // [0,16K)
    u64* bucketed = (u64*)(SHM + 16384);      // [16K,32K)
    u32* hist     = (u32*)SHM;                // [0,32K) fallback only
    float* sx1 = (float*)SHM;                 // [0,4K)   (post-rank)
    float* sy1 = (float*)(SHM + 4096);
    float* sx2 = (float*)(SHM + 8192);
    float* sy2 = (float*)(SHM + 12288);
    float* sar = (float*)(SHM + 16384);       // [16K,20K) (post-rank, bucketed dead)
    u16* items = (u16*)(SHM + 20480);         // [20K,22K)
    u16* cidx2 = (u16*)(SHM + 32768);         // [32K,34K) rank -> slot/n map
    u16* cidx  = (u16*)(SHM + 34816);         // [34K,38K) candS pos -> slot map
    u64* sel   = (u64*)(SHM + 38912);         // [38K,46K)

    if (tid < 256) { bcnt[tid] = 0u; bfill[tid] = 0u; }
    if (tid < 100) { cls_cnt[tid] = 0u; cls_fill[tid] = 0u; }
    if (tid == 0) { cntS_s = 0u; bad_s = 0u; }
    __syncthreads();                          // bad_s init visible before ORs

    // ---- read + validate 256 per-block counts, prefix scan ----
    u32 myc_raw = (tid < BLK_PER_BAT) ? cntb_g[bat * BLK_PER_BAT + tid] : 0u;
    const bool okc = (myc_raw <= SLOT_CAP);
    const u32 myc = okc ? myc_raw : 0u;       // all loops bounded by SLOT_CAP
    if (!okc) atomicOr(&bad_s, 1u);
    u32 v = myc;
#pragma unroll
    for (int off = 1; off < 64; off <<= 1) {
        u32 o = (u32)__shfl_up((int)v, off);
        if (lane >= off) v += o;
    }
    if (lane == 63) wsum[wid] = v;
    __syncthreads();
    if (tid == 0) {
        u32 s = 0;
        for (int i = 0; i < 16; ++i) { woff[i] = s; s += wsum[i]; }
        total_s = s;
    }
    __syncthreads();
    const u32 C0 = total_s;
    const bool fast = (C0 >= TOPK_K && C0 <= CAND_CAP && bad_s == 0u);
    int C;

    if (fast) {
        C = (int)C0;
        if (tid < BLK_PER_BAT && myc > 0) {
            u32 o = v - myc + woff[wid];      // exclusive offset; o+myc <= C0
            u32 gslot = ((u32)bat * BLK_PER_BAT + (u32)tid) * SLOT_CAP;
            for (u32 j = 0; j < myc; ++j) {   // <= SLOT_CAP iterations
                candS[o + j] = candk_g[gslot + j];
                cidx[o + j]  = (u16)(((u32)tid << 5) | j);
            }
        }
        __syncthreads();
    } else {
        // ------- FALLBACK (self-contained: recompute from pred) -----------
        u64* Kw = keys_g + (size_t)bat * N_DIM;
        for (int n = tid; n < N_DIM; n += 1024) {
            const float* row = pred + ((size_t)bat * N_DIM + n) * ROW_F;
            float obj = row[4];
            u32 bb = 0u; int cls = 0;
            for (int k = 5; k < 105; ++k) {
                u32 bf = __float_as_uint(row[k]) | 0x80000000u;
                if (bf > bb) { bb = bf; cls = k - 5; }
            }
            float cmax = __uint_as_float(bb & 0x7FFFFFFFu);
            float score = obj * cmax;
            bool valid = (score * cmax) >= CONF_THRE_F;
            float mval = valid ? score : -1.0f;
            u32 u  = __float_as_uint(mval);
            u32 ou = (u & 0x80000000u) ? ~u : (u | 0x80000000u);
            Kw[n] = ((u64)ou << 22) |
                    ((u64)(u32)(n ^ (N_DIM - 1)) << 7) | (u64)cls;
        }
        __syncthreads();
        const u64* K = Kw;
        for (int i = tid; i < 8192; i += 1024) hist[i] = 0u;
        __syncthreads();
        for (int n = tid * 2; n < N_DIM; n += 2048) {
            ulonglong2 k2 = *reinterpret_cast<const ulonglong2*>(K + n);
            atomicAdd(&hist[key_bin1(k2.x)], 1u);
            atomicAdd(&hist[key_bin1(k2.y)], 1u);
        }
        __syncthreads();
        if (wid == 0) scan_hist(hist, TOPK_K, &binT_s, &C1_s);
        __syncthreads();
        const u32 binT = binT_s;
        const u32 C1   = C1_s;
        __syncthreads();
        for (int i = tid; i < 8192; i += 1024) hist[i] = 0u;
        __syncthreads();
        for (int n = tid * 2; n < N_DIM; n += 2048) {
            ulonglong2 k2 = *reinterpret_cast<const ulonglong2*>(K + n);
            if (key_bin1(k2.x) == binT) atomicAdd(&hist[key_bin2(k2.x)], 1u);
            if (key_bin1(k2.y) == binT) atomicAdd(&hist[key_bin2(k2.y)], 1u);
        }
        __syncthreads();
        if (wid == 0) scan_hist(hist, TOPK_K - C1, &binT2_s, nullptr);
        __syncthreads();
        const u32 binT2 = binT2_s;
        __syncthreads();                      // hist dead -> candS region
        for (int n = tid * 2; n < N_DIM; n += 2048) {
            ulonglong2 k2 = *reinterpret_cast<const ulonglong2*>(K + n);
            u32 b1x = key_bin1(k2.x);
            if (b1x > binT || (b1x == binT && key_bin2(k2.x) >= binT2)) {
                u32 p = atomicAdd(&cntS_s, 1u);
                if (p < CAND_CAP) candS[p] = k2.x;
            }
            u32 b1y = key_bin1(k2.y);
            if (b1y > binT || (b1y == binT && key_bin2(k2.y) >= binT2)) {
                u32 p = atomicAdd(&cntS_s, 1u);
                if (p < CAND_CAP) candS[p] = k2.y;
            }
        }
        __syncthreads();
        C = (int)cntS_s; if (C > CAND_CAP) C = CAND_CAP;
    }

    // ---- min/max over candidate keys ----
    u64 kmn = ~0ull, kmx = 0ull;
    for (int i = tid; i < C; i += 1024) {
        u64 k = candS[i];
        if (k < kmn) kmn = k;
        if (k > kmx) kmx = k;
    }
#pragma unroll
    for (int off = 32; off; off >>= 1) {
        u64 a = shfl_xor64(kmn, off); if (a < kmn) kmn = a;
        u64 m = shfl_xor64(kmx, off); if (m > kmx) kmx = m;
    }
    if (lane == 0) { wmin_s[wid] = kmn; wmax_s[wid] = kmx; }
    __syncthreads();
    if (tid == 0) {
        u64 mn = wmin_s[0], mx = wmax_s[0];
        for (int i = 1; i < 16; ++i) {
            if (wmin_s[i] < mn) mn = wmin_s[i];
            if (wmax_s[i] > mx) mx = wmax_s[i];
        }
        kmin_s = mn;
        u64 d = mx - mn;
        int pos = 63 - __clzll(d | 1ull);
        shift_s = (pos > 7) ? (u32)(pos - 7) : 0u;
    }
    __syncthreads();
    const u64 kmin = kmin_s;
    const u32 shift = shift_s;

    // ---- bucket histogram (exact, monotonic bucketing) ----
    const bool own0 = (tid < C);
    const bool own1 = (tid + 1024 < C);
    u64 key0 = 0, key1 = 0; u32 bkt0 = 0, bkt1 = 0;
    if (own0) { key0 = candS[tid];        bkt0 = (u32)((key0 - kmin) >> shift); atomicAdd(&bcnt[bkt0], 1u); }
    if (own1) { key1 = candS[tid + 1024]; bkt1 = (u32)((key1 - kmin) >> shift); atomicAdd(&bcnt[bkt1], 1u); }
    __syncthreads();
    if (wid == 0) {   // exclusive prefix over 256 bins
        u32 s0 = bcnt[lane * 4], s1 = bcnt[lane * 4 + 1],
            s2 = bcnt[lane * 4 + 2], s3 = bcnt[lane * 4 + 3];
        u32 tot = s0 + s1 + s2 + s3;
        u32 incl = tot;
#pragma unroll
        for (int off = 1; off < 64; off <<= 1) {
            u32 vv = (u32)__shfl_up((int)incl, off);
            if (lane >= off) incl += vv;
        }
        u32 ex = incl - tot;
        bstart[lane * 4]     = ex;
        bstart[lane * 4 + 1] = ex + s0;
        bstart[lane * 4 + 2] = ex + s0 + s1;
        bstart[lane * 4 + 3] = ex + s0 + s1 + s2;
        if (lane == 63) bstart[256] = incl;
    }
    __syncthreads();
    if (own0) { u32 p = bstart[bkt0] + atomicAdd(&bfill[bkt0], 1u); bucketed[p] = key0; }
    if (own1) { u32 p = bstart[bkt1] + atomicAdd(&bfill[bkt1], 1u); bucketed[p] = key1; }
    __syncthreads();

    // ---- exact rank within bucket + write rank-ordered NMS inputs ----
    u32 rank0 = ~0u, rank1 = ~0u; float area0 = 0.f, area1 = 0.f;
#define RANK_ONE(own, mykey, mybkt, slot, rankv, areav)                       \
    if (own) {                                                                \
        u32 lo = bstart[mybkt], hi = bstart[mybkt + 1];                       \
        u32 g = 0;                                                            \
        for (u32 p = lo; p < hi; ++p) g += (bucketed[p] > (mykey));           \
        u32 rk = ((u32)C - hi) + g;                                           \
        if (rk < TOPK_K) {                                                    \
            rankv = rk;                                                       \
            float4 bx;                                                        \
            if (fast) {                                                       \
                u32 s2 = (u32)cidx[slot];                                     \
                bx = candb_g[((u32)bat << 13) | s2];                          \
                cidx2[rk] = (u16)s2;                                          \
            } else {                                                          \
                int n = (N_DIM - 1) - (int)(((mykey) >> 7) & (u64)(N_DIM - 1)); \
                const float* row = pred + ((size_t)bat * N_DIM + n) * ROW_F;  \
                bx = make_float4(row[0], row[1], row[2], row[3]);             \
                cidx2[rk] = (u16)n;                                           \
            }                                                                 \
            int lab = (int)((mykey) & 0x7Full);                               \
            float x1 = bx.x - bx.z * 0.5f, y1 = bx.y - bx.w * 0.5f;           \
            float x2 = bx.z + x1,          y2 = bx.w + y1;                    \
            float off = (float)lab * OFFSET_F;                                \
            float nx1 = x1 + off, ny1 = y1 + off;                             \
            float nx2 = x2 + off, ny2 = y2 + off;                             \
            areav = (nx2 - nx1) * (ny2 - ny1);                                \
            sel[rk] = (mykey);                                                \
            sx1[rk] = nx1; sy1[rk] = ny1; sx2[rk] = nx2; sy2[rk] = ny2;       \
        }                                                                     \
    }
    RANK_ONE(own0, key0, bkt0, tid,        rank0, area0)
    RANK_ONE(own1, key1, bkt1, tid + 1024, rank1, area1)
#undef RANK_ONE
    __syncthreads();                          // bucketed dead
    if (rank0 != ~0u) sar[rank0] = area0;
    if (rank1 != ~0u) sar[rank1] = area1;

    // ---- per-rank decode + class lists ----
    u64 key = sel[tid];
    int lab = (int)(key & 0x7Full);
    u32 ou  = (u32)(key >> 22);
    u32 ob  = (ou & 0x80000000u) ? (ou & 0x7FFFFFFFu) : ~ou;
    float score = __uint_as_float(ob);
    bool validk = (score >= 0.0f);
    atomicAdd(&cls_cnt[lab], 1u);
    __syncthreads();
    if (wid == 0) {   // exclusive prefix over 100 class bins
        u32 s0 = (lane < 50) ? cls_cnt[lane * 2] : 0u;
        u32 s1 = (lane < 50) ? cls_cnt[lane * 2 + 1] : 0u;
        u32 tot = s0 + s1;
        u32 incl = tot;
#pragma unroll
        for (int off = 1; off < 64; off <<= 1) {
            u32 vv = (u32)__shfl_up((int)incl, off);
            if (lane >= off) incl += vv;
        }
        u32 ex = incl - tot;
        if (lane < 50) { cls_start[lane * 2] = ex; cls_start[lane * 2 + 1] = ex + s0; }
    }
    __syncthreads();
    {
        u32 p = cls_start[lab] + atomicAdd(&cls_fill[lab], 1u);
        items[p] = (u16)tid;
    }
    __syncthreads();

    const float nx1 = sx1[tid], ny1 = sy1[tid], nx2 = sx2[tid], ny2 = sy2[tid];
    const float area = sar[tid];

    // ---- suppression-mask column, same-class partners only (~10 IoUs) ----
    // Cross-class IoU is exactly 0 (class offset 241 >= extent bound 231).
    u64 m0=0,m1=0,m2=0,m3=0,m4=0,m5=0,m6=0,m7=0,
        m8=0,m9=0,m10=0,m11=0,m12=0,m13=0,m14=0,m15=0;
    {
        const int s0 = (int)cls_start[lab];
        const int e0 = s0 + (int)cls_cnt[lab];
        for (int p = s0; p < e0; ++p) {
            int i = (int)items[p];
            if (i == tid) continue;
            float ix1 = fmaxf(sx1[i], nx1), iy1 = fmaxf(sy1[i], ny1);
            float ix2 = fminf(sx2[i], nx2), iy2 = fminf(sy2[i], ny2);
            float iw = fmaxf(ix2 - ix1, 0.0f), ih = fmaxf(iy2 - iy1, 0.0f);
            float inter = iw * ih;
            float iou = inter / (sar[i] + area - inter + 1e-12f);
            if (iou > NMS_THRE_F) {
                u64 bit = 1ull << (i & 63);
                int ch = i >> 6;
                m0  |= (ch == 0)  ? bit : 0ull;  m1  |= (ch == 1)  ? bit : 0ull;
                m2  |= (ch == 2)  ? bit : 0ull;  m3  |= (ch == 3)  ? bit : 0ull;
                m4  |= (ch == 4)  ? bit : 0ull;  m5  |= (ch == 5)  ? bit : 0ull;
                m6  |= (ch == 6)  ? bit : 0ull;  m7  |= (ch == 7)  ? bit : 0ull;
                m8  |= (ch == 8)  ? bit : 0ull;  m9  |= (ch == 9)  ? bit : 0ull;
                m10 |= (ch == 10) ? bit : 0ull;  m11 |= (ch == 11) ? bit : 0ull;
                m12 |= (ch == 12) ? bit : 0ull;  m13 |= (ch == 13) ? bit : 0ull;
                m14 |= (ch == 14) ? bit : 0ull;  m15 |= (ch == 15) ? bit : 0ull;
            }
        }
    }

    // ---- greedy scan, 16 chunks; serial work only on conflicted lanes ----
    bool supp = false, keepb = false;
#define CHUNK_STEP(c, mc)                                                     \
    {                                                                         \
        if (wid == (c)) {                                                     \
            u64 W  = (mc);                                                    \
            u64 vm = __ballot(validk && !supp);                               \
            u64 S  = __ballot(W != 0ull);                                     \
            u64 km = vm & ~S;                                                 \
            u64 suppm = 0ull, mm = S;                                         \
            while (mm) {                                                      \
                int i = __builtin_ctzll(mm); mm &= mm - 1ull;                 \
                u64 Wi = shfl64(W, i);                                        \
                if (((vm >> i) & 1ull) && !((suppm >> i) & 1ull)) {           \
                    km |= 1ull << i; suppm |= Wi;                             \
                }                                                             \
            }                                                                 \
            keepb = ((km >> lane) & 1ull) != 0ull;                            \
            if (lane == 0) keepm_s[(c)] = km;                                 \
        }                                                                     \
        __syncthreads();                                                      \
        if (wid > (c) && ((mc) & keepm_s[(c)])) supp = true;                  \
    }
    CHUNK_STEP(0, m0)   CHUNK_STEP(1, m1)   CHUNK_STEP(2, m2)   CHUNK_STEP(3, m3)
    CHUNK_STEP(4, m4)   CHUNK_STEP(5, m5)   CHUNK_STEP(6, m6)   CHUNK_STEP(7, m7)
    CHUNK_STEP(8, m8)   CHUNK_STEP(9, m9)   CHUNK_STEP(10, m10) CHUNK_STEP(11, m11)
    CHUNK_STEP(12, m12) CHUNK_STEP(13, m13) CHUNK_STEP(14, m14) CHUNK_STEP(15, m15)
#undef CHUNK_STEP

    // ---- output (re-gather raw box via rank->slot/n map; same fp ops) ----
    float keepf = keepb ? 1.0f : 0.0f;
    float4 bx;
    if (fast) {
        bx = candb_g[((u32)bat << 13) | (u32)cidx2[tid]];
    } else {
        int n2 = (int)cidx2[tid];
        const float* row = pred + ((size_t)bat * N_DIM + n2) * ROW_F;
        bx = make_float4(row[0], row[1], row[2], row[3]);
    }
    float x1 = bx.x - bx.z * 0.5f, y1 = bx.y - bx.w * 0.5f;
    float x2 = bx.z + x1,          y2 = bx.w + y1;
    float2* o2 = (float2*)(out + ((size_t)bat * TOPK_K + tid) * 6);
    o2[0] = make_float2(x1 * keepf, y1 * keepf);
    o2[1] = make_float2(x2 * keepf, y2 * keepf);
    o2[2] = make_float2(score * keepf, (float)lab * keepf);
}

// ---------------------------------------------------------------------------
extern "C" void kernel_launch(void* const* d_in, const int* in_sizes, int n_in,
                              void* d_out, int out_size, void* d_ws, size_t ws_size,
                              hipStream_t stream) {
    const float* pred = (const float*)d_in[0];
    float* out = (float*)d_out;

    // workspace (candk/candb/cntb written every call; done is a monotonically
    // growing counter — only mod-256 boundary crossings are used)
    u64*    candk = (u64*)d_ws;                                    // 512 KB
    float4* candb = (float4*)((char*)d_ws + (512u << 10));         // 1 MB
    u32*    cntb  = (u32*)((char*)d_ws + (1536u << 10));           // 8 KB
    u32*    done  = (u32*)((char*)d_ws + (1544u << 10));           // 1 KB
    u64*    keys  = (u64*)((char*)d_ws + (1600u << 10));           // 2 MB (fallback only)

    fused_kernel<<<(B_DIM * N_DIM) / ROWS_PER_BLK, 1024, 0, stream>>>(
        pred, keys, candk, candb, cntb, done, out);
}

// Round 15
// 40.484 us; speedup vs baseline: 15.0872x; 15.0872x over previous
//
#include <hip/hip_runtime.h>
#include <hip/hip_bf16.h>

// Keep every fp op matching numpy/jax f32 op-by-op rounding (no fma fusion):
#pragma clang fp contract(off)

#define NUM_CLASSES 100
#define B_DIM 8
#define N_DIM 32768
#define TOPK_K 1024
#define ROW_F 105
#define CONF_THRE_F 0.001f
#define NMS_THRE_F 0.65f
#define OFFSET_F 241.0f   // MAX_DIM + 1
#define T0_F 0.95f        // prefilter threshold (fast path iff 1024<=C<=2048)
#define CAND_CAP 2048
#define BLK_PER_BAT 512   // 64-row decode blocks per batch
#define SLOT_CAP 16       // per-block candidate slots (P(>16) ~ 1e-10)

typedef unsigned long long u64;
typedef unsigned int u32;

__device__ __forceinline__ u64 shfl64(u64 v, int src) {
    int lo = __shfl((int)(v & 0xFFFFFFFFull), src);
    int hi = __shfl((int)(v >> 32), src);
    return ((u64)(u32)hi << 32) | (u32)lo;
}
__device__ __forceinline__ u64 shfl_xor64(u64 v, int mask) {
    int lo = __shfl_xor((int)(v & 0xFFFFFFFFull), mask);
    int hi = __shfl_xor((int)(v >> 32), mask);
    return ((u64)(u32)hi << 32) | (u32)lo;
}

// key layout (54 bits): [ou(32) << 22] | [(32767-n)(15) << 7] | class(7)
__device__ __forceinline__ u32 key_bin1(u64 k) {   // ou bits 30..18, 0 if invalid
    return ((k >> 53) & 1ull) ? (u32)((k >> 40) & 0x1FFFull) : 0u;
}
__device__ __forceinline__ u32 key_bin2(u64 k) {   // ou bits 17..5
    return (u32)((k >> 27) & 0x1FFFull);
}

// ---------------------------------------------------------------------------
// Kernel 1: decode. One 64-row chunk per 256-thread block (26.88 KB LDS ->
// 5 blocks/CU). Stage with 7 in-flight float4 loads; scan with 4 threads/row
// (25 class scores each) + 2-step shfl_xor lexicographic max; wave-ballot
// append of prefiltered candidates (key + raw box).
// ---------------------------------------------------------------------------
__global__ __launch_bounds__(256) void decode_kernel(const float* __restrict__ pred,
                                                     u64* __restrict__ candk,
                                                     float4* __restrict__ candb,
                                                     u32* __restrict__ cntb) {
    __shared__ float buf[64 * ROW_F];            // 26880 B
    __shared__ u32 bcount;
    __shared__ u64 lkey[SLOT_CAP];
    __shared__ float4 lbox[SLOT_CAP];
    const int tid = threadIdx.x;
    const int lane = tid & 63;
    const int blk = blockIdx.x;                  // 4096 blocks
    const int rb  = blk << 6;                    // 64 rows per block
    const int bat = blk >> 9;
    const int bi  = blk & (BLK_PER_BAT - 1);

    if (tid == 0) bcount = 0u;

    // ---- stage 64 rows = 1680 float4 (issue all loads, then write LDS) ----
    {
        const float4* src = reinterpret_cast<const float4*>(pred + (size_t)rb * ROW_F);
        float4* dst = reinterpret_cast<float4*>(buf);
        float4 v0 = src[tid];
        float4 v1 = src[tid + 256];
        float4 v2 = src[tid + 512];
        float4 v3 = src[tid + 768];
        float4 v4 = src[tid + 1024];
        float4 v5 = src[tid + 1280];
        float4 v6;
        if (tid < 144) v6 = src[tid + 1536];
        dst[tid]        = v0;
        dst[tid + 256]  = v1;
        dst[tid + 512]  = v2;
        dst[tid + 768]  = v3;
        dst[tid + 1024] = v4;
        dst[tid + 1280] = v5;
        if (tid < 144) dst[tid + 1536] = v6;
    }
    __syncthreads();

    // ---- scan: 4 threads per row ----
    const int row = tid >> 2;                    // 0..63
    const int sub = tid & 3;
    const float* R = buf + row * ROW_F;

    u64 kk;
    {
        u32 bb = 0u, cz = 0u;
        const int p0 = 5 + sub * 25;
#pragma unroll
        for (int k = 0; k < 25; ++k) {
            // class scores >= 0: bit order == float order; strict '>' with
            // ascending position keeps the FIRST max (== jnp.argmax).
            u32 bf = __float_as_uint(R[p0 + k]) | 0x80000000u;
            u32 cf = (u32)(104 - (p0 + k));      // == 99 - class; bigger = earlier
            if (bf > bb) { bb = bf; cz = cf; }
        }
        kk = ((u64)bb << 7) | (u64)cz;
        u64 o = shfl_xor64(kk, 1); if (o > kk) kk = o;
        o     = shfl_xor64(kk, 2); if (o > kk) kk = o;
    }
    const u32 bb = (u32)(kk >> 7);
    const int cls = 99 - (int)(kk & 0x7Full);
    const float cmax = __uint_as_float(bb & 0x7FFFFFFFu);
    const float obj = R[4];
    const float score = obj * cmax;              // reference op order
    const bool valid = (score * cmax) >= CONF_THRE_F;
    const float mval = valid ? score : -1.0f;

    if (sub == 0 && mval >= T0_F) {
        const u32 u  = __float_as_uint(mval);
        const u32 ou = (u & 0x80000000u) ? ~u : (u | 0x80000000u);
        const int r = rb + row;
        const u64 key = ((u64)ou << 22) |
                        ((u64)(u32)((r & (N_DIM - 1)) ^ (N_DIM - 1)) << 7) |
                        (u64)cls;
        u32 p = atomicAdd(&bcount, 1u);
        if (p < SLOT_CAP) {
            lkey[p] = key;
            lbox[p] = make_float4(R[0], R[1], R[2], R[3]);
        }
    }
    __syncthreads();

    const u32 c = bcount;
    const u32 gslot = ((u32)bat * BLK_PER_BAT + (u32)bi) * SLOT_CAP;
    if (tid < c && tid < SLOT_CAP) {
        candk[gslot + tid] = lkey[tid];
        candb[gslot + tid] = lbox[tid];
    }
    if (tid == 0) cntb[bat * BLK_PER_BAT + bi] = (c <= SLOT_CAP) ? c : 0xFFFFu;
}

// ---------------------------------------------------------------------------
// wave-0 suffix scan over 8192-bin LDS hist (rotated reads: conflict-free).
// FALLBACK path only.
// ---------------------------------------------------------------------------
__device__ __forceinline__ void scan_hist(const u32* h, u32 target,
                                          u32* binT_out, u32* c1_out) {
    const int lane = threadIdx.x & 63;
    const u32* hl = h + lane * 128;
    u32 partial = 0;
    for (int k = 0; k < 128; ++k) partial += hl[(k + lane) & 127];
    u32 v = partial;
#pragma unroll
    for (int off = 1; off < 64; off <<= 1) {
        u32 o = __shfl_down(v, off);
        if (lane + off < 64) v += o;
    }
    u32 above = v - partial;
    if (above < target && above + partial >= target) {
        u32 cum = above;
        int bin = lane * 128 + 127;
        for (;; --bin) {
            cum += h[bin];
            if (cum >= target) break;
        }
        *binT_out = (u32)bin;
        if (c1_out) *c1_out = cum - h[bin];
    }
}

// ---------------------------------------------------------------------------
// Kernel 2: gather per-block candidate slots (prefix-scan of 512 counts), or
// recompute-keys + histogram-select fallback -> exact bucket rank ->
// class-sparse mask NMS -> output. One 1024-thread block per batch.
// ---------------------------------------------------------------------------
__global__ __launch_bounds__(1024) void selnms_kernel(const float* __restrict__ pred,
                                                      u64* __restrict__ keys_g,
                                                      const u64* __restrict__ candk_g,
                                                      const float4* __restrict__ candb_g,
                                                      const u32* __restrict__ cntb_g,
                                                      float* __restrict__ out) {
    const int b    = blockIdx.x;
    const int tid  = threadIdx.x;
    const int wid  = tid >> 6;
    const int lane = tid & 63;

    __shared__ u64 sel[TOPK_K];                    // 8 KB
    alignas(16) __shared__ char SC[49152];         // 48 KB phase-reused
    __shared__ unsigned short cidx[CAND_CAP];      // 4 KB (fast-path box map)
    __shared__ u64 keepm_s[16];
    __shared__ u64 wmin_s[16], wmax_s[16];
    __shared__ u64 kmin_s;
    __shared__ u32 shift_s;
    __shared__ u32 wsum[8], woff[8], total_s;
    __shared__ u32 bcnt[256], bfill[256], bstart[257];
    __shared__ u32 cls_cnt[100], cls_start[100], cls_fill[100];
    __shared__ u32 binT_s, binT2_s, C1_s, cntS_s;

    u64* candS    = (u64*)SC;                      // [0,16K)
    u64* bucketed = (u64*)(SC + 16384);            // [16K,32K)
    u32* hist     = (u32*)(SC + 16384);            // [16K,48K) fallback only
    float* sx1 = (float*)SC;                       // [0,4K)   (after rank)
    float* sy1 = (float*)(SC + 4096);
    float* sx2 = (float*)(SC + 8192);
    float* sy2 = (float*)(SC + 12288);
    float* sar = (float*)(SC + 16384);             // [16K,20K) (after rank+bar)
    unsigned short* items = (unsigned short*)(SC + 20480);  // [20K,22K)
    float4* rbox = (float4*)(SC + 32768);          // [32K,48K)

    if (tid < 256) { bcnt[tid] = 0u; bfill[tid] = 0u; }
    if (tid < 100) { cls_cnt[tid] = 0u; cls_fill[tid] = 0u; }
    if (tid == 0) cntS_s = 0u;

    // ---- prefix scan of 512 per-block counts ----
    u32 myc = (tid < BLK_PER_BAT) ? cntb_g[b * BLK_PER_BAT + tid] : 0u;
    u32 v = myc;
#pragma unroll
    for (int off = 1; off < 64; off <<= 1) {
        u32 o = (u32)__shfl_up((int)v, off);
        if (lane >= off) v += o;
    }
    if (tid < BLK_PER_BAT && lane == 63) wsum[wid] = v;
    __syncthreads();
    if (tid == 0) {
        u32 s = 0;
        for (int i = 0; i < 8; ++i) { woff[i] = s; s += wsum[i]; }
        total_s = s;
    }
    __syncthreads();
    const u32 C0 = total_s;                        // sentinel -> huge -> fallback
    const bool fast = (C0 >= TOPK_K && C0 <= CAND_CAP);
    int C;

    if (fast) {
        C = (int)C0;
        if (tid < BLK_PER_BAT && myc > 0) {
            u32 o = v - myc + woff[wid];           // exclusive offset
            u32 gslot = ((u32)b * BLK_PER_BAT + (u32)tid) * SLOT_CAP;
            for (u32 j = 0; j < myc; ++j) {
                candS[o + j] = candk_g[gslot + j];
                cidx[o + j]  = (unsigned short)((tid << 4) + j);
            }
        }
        __syncthreads();
    } else {
        // ------- FALLBACK (correct for any data; never taken here) --------
        // recompute keys for this batch from pred, then two-level select
        u64* Kw = keys_g + (size_t)b * N_DIM;
        for (int n = tid; n < N_DIM; n += 1024) {
            const float* row = pred + ((size_t)b * N_DIM + n) * ROW_F;
            float obj = row[4];
            u32 bb = 0u; int cls = 0;
            for (int k = 5; k < 105; ++k) {
                u32 bf = __float_as_uint(row[k]) | 0x80000000u;
                if (bf > bb) { bb = bf; cls = k - 5; }
            }
            float cmax = __uint_as_float(bb & 0x7FFFFFFFu);
            float score = obj * cmax;
            bool valid = (score * cmax) >= CONF_THRE_F;
            float mval = valid ? score : -1.0f;
            u32 u  = __float_as_uint(mval);
            u32 ou = (u & 0x80000000u) ? ~u : (u | 0x80000000u);
            Kw[n] = ((u64)ou << 22) |
                    ((u64)(u32)(n ^ (N_DIM - 1)) << 7) | (u64)cls;
        }
        __syncthreads();
        const u64* K = Kw;
        for (int i = tid; i < 8192; i += 1024) hist[i] = 0u;
        __syncthreads();
        for (int n = tid * 2; n < N_DIM; n += 2048) {
            ulonglong2 k2 = *reinterpret_cast<const ulonglong2*>(K + n);
            atomicAdd(&hist[key_bin1(k2.x)], 1u);
            atomicAdd(&hist[key_bin1(k2.y)], 1u);
        }
        __syncthreads();
        if (wid == 0) scan_hist(hist, TOPK_K, &binT_s, &C1_s);
        __syncthreads();
        const u32 binT = binT_s;
        const u32 C1   = C1_s;
        __syncthreads();
        for (int i = tid; i < 8192; i += 1024) hist[i] = 0u;
        __syncthreads();
        for (int n = tid * 2; n < N_DIM; n += 2048) {
            ulonglong2 k2 = *reinterpret_cast<const ulonglong2*>(K + n);
            if (key_bin1(k2.x) == binT) atomicAdd(&hist[key_bin2(k2.x)], 1u);
            if (key_bin1(k2.y) == binT) atomicAdd(&hist[key_bin2(k2.y)], 1u);
        }
        __syncthreads();
        if (wid == 0) scan_hist(hist, TOPK_K - C1, &binT2_s, nullptr);
        __syncthreads();
        const u32 binT2 = binT2_s;
        __syncthreads();                           // hist dead
        for (int n = tid * 2; n < N_DIM; n += 2048) {
            ulonglong2 k2 = *reinterpret_cast<const ulonglong2*>(K + n);
            u32 b1x = key_bin1(k2.x);
            if (b1x > binT || (b1x == binT && key_bin2(k2.x) >= binT2)) {
                u32 p = atomicAdd(&cntS_s, 1u);
                if (p < CAND_CAP) candS[p] = k2.x;
            }
            u32 b1y = key_bin1(k2.y);
            if (b1y > binT || (b1y == binT && key_bin2(k2.y) >= binT2)) {
                u32 p = atomicAdd(&cntS_s, 1u);
                if (p < CAND_CAP) candS[p] = k2.y;
            }
        }
        __syncthreads();
        C = (int)cntS_s; if (C > CAND_CAP) C = CAND_CAP;
    }

    // ---- min/max over candidate keys ----
    u64 kmn = ~0ull, kmx = 0ull;
    for (int i = tid; i < C; i += 1024) {
        u64 k = candS[i];
        if (k < kmn) kmn = k;
        if (k > kmx) kmx = k;
    }
#pragma unroll
    for (int off = 32; off; off >>= 1) {
        u64 a = shfl_xor64(kmn, off); if (a < kmn) kmn = a;
        u64 m = shfl_xor64(kmx, off); if (m > kmx) kmx = m;
    }
    if (lane == 0) { wmin_s[wid] = kmn; wmax_s[wid] = kmx; }
    __syncthreads();
    if (tid == 0) {
        u64 mn = wmin_s[0], mx = wmax_s[0];
        for (int i = 1; i < 16; ++i) {
            if (wmin_s[i] < mn) mn = wmin_s[i];
            if (wmax_s[i] > mx) mx = wmax_s[i];
        }
        kmin_s = mn;
        u64 d = mx - mn;
        int pos = 63 - __clzll(d | 1ull);
        shift_s = (pos > 7) ? (u32)(pos - 7) : 0u;
    }
    __syncthreads();
    const u64 kmin = kmin_s;
    const u32 shift = shift_s;

    // ---- bucket histogram (exact, monotonic bucketing) ----
    const bool own0 = (tid < C);
    const bool own1 = (tid + 1024 < C);
    u64 key0 = 0, key1 = 0; u32 bkt0 = 0, bkt1 = 0;
    if (own0) { key0 = candS[tid];        bkt0 = (u32)((key0 - kmin) >> shift); atomicAdd(&bcnt[bkt0], 1u); }
    if (own1) { key1 = candS[tid + 1024]; bkt1 = (u32)((key1 - kmin) >> shift); atomicAdd(&bcnt[bkt1], 1u); }
    __syncthreads();
    if (wid == 0) {   // exclusive prefix over 256 bins
        u32 s0 = bcnt[lane * 4], s1 = bcnt[lane * 4 + 1],
            s2 = bcnt[lane * 4 + 2], s3 = bcnt[lane * 4 + 3];
        u32 tot = s0 + s1 + s2 + s3;
        u32 incl = tot;
#pragma unroll
        for (int off = 1; off < 64; off <<= 1) {
            u32 vv = (u32)__shfl_up((int)incl, off);
            if (lane >= off) incl += vv;
        }
        u32 ex = incl - tot;
        bstart[lane * 4]     = ex;
        bstart[lane * 4 + 1] = ex + s0;
        bstart[lane * 4 + 2] = ex + s0 + s1;
        bstart[lane * 4 + 3] = ex + s0 + s1 + s2;
        if (lane == 63) bstart[256] = incl;
    }
    __syncthreads();
    if (own0) { u32 p = bstart[bkt0] + atomicAdd(&bfill[bkt0], 1u); bucketed[p] = key0; }
    if (own1) { u32 p = bstart[bkt1] + atomicAdd(&bfill[bkt1], 1u); bucketed[p] = key1; }
    __syncthreads();

    // ---- exact rank within bucket + write rank-ordered NMS inputs ----
    u32 rank0 = ~0u, rank1 = ~0u; float area0 = 0.f, area1 = 0.f;
#define RANK_ONE(own, mykey, mybkt, slot, rankv, areav)                       \
    if (own) {                                                                \
        u32 lo = bstart[mybkt], hi = bstart[mybkt + 1];                       \
        u32 g = 0;                                                            \
        for (u32 p = lo; p < hi; ++p) g += (bucketed[p] > (mykey));           \
        u32 rk = ((u32)C - hi) + g;                                           \
        if (rk < TOPK_K) {                                                    \
            rankv = rk;                                                       \
            float4 bx;                                                        \
            if (fast) bx = candb_g[((u32)b << 13) | (u32)cidx[slot]];         \
            else {                                                            \
                int n = (N_DIM - 1) - (int)(((mykey) >> 7) & (u64)(N_DIM - 1)); \
                const float* row = pred + ((size_t)b * N_DIM + n) * ROW_F;    \
                bx = make_float4(row[0], row[1], row[2], row[3]);             \
            }                                                                 \
            int lab = (int)((mykey) & 0x7Full);                               \
            float x1 = bx.x - bx.z * 0.5f, y1 = bx.y - bx.w * 0.5f;           \
            float x2 = bx.z + x1,          y2 = bx.w + y1;                    \
            float off = (float)lab * OFFSET_F;                                \
            float nx1 = x1 + off, ny1 = y1 + off;                             \
            float nx2 = x2 + off, ny2 = y2 + off;                             \
            areav = (nx2 - nx1) * (ny2 - ny1);                                \
            sel[rk] = (mykey);                                                \
            sx1[rk] = nx1; sy1[rk] = ny1; sx2[rk] = nx2; sy2[rk] = ny2;       \
            rbox[rk] = make_float4(x1, y1, x2, y2);                           \
        }                                                                     \
    }
    RANK_ONE(own0, key0, bkt0, tid,        rank0, area0)
    RANK_ONE(own1, key1, bkt1, tid + 1024, rank1, area1)
#undef RANK_ONE
    __syncthreads();                               // bucketed dead
    if (rank0 != ~0u) sar[rank0] = area0;
    if (rank1 != ~0u) sar[rank1] = area1;

    // ---- per-rank decode + class lists ----
    u64 key = sel[tid];
    int lab = (int)(key & 0x7Full);
    u32 ou  = (u32)(key >> 22);
    u32 ob  = (ou & 0x80000000u) ? (ou & 0x7FFFFFFFu) : ~ou;
    float score = __uint_as_float(ob);
    bool validk = (score >= 0.0f);
    atomicAdd(&cls_cnt[lab], 1u);
    __syncthreads();
    if (wid == 0) {   // exclusive prefix over 100 class bins
        u32 s0 = (lane < 50) ? cls_cnt[lane * 2] : 0u;
        u32 s1 = (lane < 50) ? cls_cnt[lane * 2 + 1] : 0u;
        u32 tot = s0 + s1;
        u32 incl = tot;
#pragma unroll
        for (int off = 1; off < 64; off <<= 1) {
            u32 vv = (u32)__shfl_up((int)incl, off);
            if (lane >= off) incl += vv;
        }
        u32 ex = incl - tot;
        if (lane < 50) { cls_start[lane * 2] = ex; cls_start[lane * 2 + 1] = ex + s0; }
    }
    __syncthreads();
    {
        u32 p = cls_start[lab] + atomicAdd(&cls_fill[lab], 1u);
        items[p] = (unsigned short)tid;
    }
    __syncthreads();

    const float nx1 = sx1[tid], ny1 = sy1[tid], nx2 = sx2[tid], ny2 = sy2[tid];
    const float area = sar[tid];

    // ---- suppression-mask column, same-class partners only (~10 IoUs) ----
    // Cross-class IoU is exactly 0 (class offset 241 >= extent bound 231).
    u64 m0=0,m1=0,m2=0,m3=0,m4=0,m5=0,m6=0,m7=0,
        m8=0,m9=0,m10=0,m11=0,m12=0,m13=0,m14=0,m15=0;
    {
        const int s0 = (int)cls_start[lab];
        const int e0 = s0 + (int)cls_cnt[lab];
        for (int p = s0; p < e0; ++p) {
            int i = (int)items[p];
            if (i == tid) continue;
            float ix1 = fmaxf(sx1[i], nx1), iy1 = fmaxf(sy1[i], ny1);
            float ix2 = fminf(sx2[i], nx2), iy2 = fminf(sy2[i], ny2);
            float iw = fmaxf(ix2 - ix1, 0.0f), ih = fmaxf(iy2 - iy1, 0.0f);
            float inter = iw * ih;
            float iou = inter / (sar[i] + area - inter + 1e-12f);
            if (iou > NMS_THRE_F) {
                u64 bit = 1ull << (i & 63);
                int ch = i >> 6;
                m0  |= (ch == 0)  ? bit : 0ull;  m1  |= (ch == 1)  ? bit : 0ull;
                m2  |= (ch == 2)  ? bit : 0ull;  m3  |= (ch == 3)  ? bit : 0ull;
                m4  |= (ch == 4)  ? bit : 0ull;  m5  |= (ch == 5)  ? bit : 0ull;
                m6  |= (ch == 6)  ? bit : 0ull;  m7  |= (ch == 7)  ? bit : 0ull;
                m8  |= (ch == 8)  ? bit : 0ull;  m9  |= (ch == 9)  ? bit : 0ull;
                m10 |= (ch == 10) ? bit : 0ull;  m11 |= (ch == 11) ? bit : 0ull;
                m12 |= (ch == 12) ? bit : 0ull;  m13 |= (ch == 13) ? bit : 0ull;
                m14 |= (ch == 14) ? bit : 0ull;  m15 |= (ch == 15) ? bit : 0ull;
            }
        }
    }

    // ---- greedy scan, 16 chunks; serial work only on conflicted lanes ----
    bool supp = false, keepb = false;
#define CHUNK_STEP(c, mc)                                                     \
    {                                                                         \
        if (wid == (c)) {                                                     \
            u64 W  = (mc);                                                    \
            u64 vm = __ballot(validk && !supp);                               \
            u64 S  = __ballot(W != 0ull);                                     \
            u64 km = vm & ~S;                                                 \
            u64 suppm = 0ull, mm = S;                                         \
            while (mm) {                                                      \
                int i = __builtin_ctzll(mm); mm &= mm - 1ull;                 \
                u64 Wi = shfl64(W, i);                                        \
                if (((vm >> i) & 1ull) && !((suppm >> i) & 1ull)) {           \
                    km |= 1ull << i; suppm |= Wi;                             \
                }                                                             \
            }                                                                 \
            keepb = ((km >> lane) & 1ull) != 0ull;                            \
            if (lane == 0) keepm_s[(c)] = km;                                 \
        }                                                                     \
        __syncthreads();                                                      \
        if (wid > (c) && ((mc) & keepm_s[(c)])) supp = true;                  \
    }
    CHUNK_STEP(0, m0)   CHUNK_STEP(1, m1)   CHUNK_STEP(2, m2)   CHUNK_STEP(3, m3)
    CHUNK_STEP(4, m4)   CHUNK_STEP(5, m5)   CHUNK_STEP(6, m6)   CHUNK_STEP(7, m7)
    CHUNK_STEP(8, m8)   CHUNK_STEP(9, m9)   CHUNK_STEP(10, m10) CHUNK_STEP(11, m11)
    CHUNK_STEP(12, m12) CHUNK_STEP(13, m13) CHUNK_STEP(14, m14) CHUNK_STEP(15, m15)
#undef CHUNK_STEP

    float keepf = keepb ? 1.0f : 0.0f;
    float4 rb4 = rbox[tid];
    float2* o2 = (float2*)(out + ((size_t)b * TOPK_K + tid) * 6);
    o2[0] = make_float2(rb4.x * keepf, rb4.y * keepf);
    o2[1] = make_float2(rb4.z * keepf, rb4.w * keepf);
    o2[2] = make_float2(score * keepf, (float)lab * keepf);
}

// ---------------------------------------------------------------------------
extern "C" void kernel_launch(void* const* d_in, const int* in_sizes, int n_in,
                              void* d_out, int out_size, void* d_ws, size_t ws_size,
                              hipStream_t stream) {
    const float* pred = (const float*)d_in[0];
    float* out = (float*)d_out;

    // workspace layout (all regions written-before-read every call)
    u64*    candk = (u64*)d_ws;                                        // 512 KB
    float4* candb = (float4*)((char*)d_ws + (512u << 10));             // 1 MB
    u32*    cntb  = (u32*)((char*)d_ws + (1536u << 10));               // 16 KB
    u64*    keys  = (u64*)((char*)d_ws + (2048u << 10));               // 2 MB (fallback only)

    decode_kernel<<<(B_DIM * N_DIM) / 64, 256, 0, stream>>>(pred, candk, candb, cntb);
    selnms_kernel<<<B_DIM, 1024, 0, stream>>>(pred, keys, candk, candb, cntb, out);
}